// Round 6
// baseline (180.244 us; speedup 1.0000x reference)
//
#include <hip/hip_runtime.h>
#include <hip/hip_cooperative_groups.h>
#include <math.h>

namespace cg = cooperative_groups;

#define LN_EPS 1e-5f

// Problem: B=8 scenes, A=16 agents, L=80 lanes, D=128, H=6.
// N=768 nodes (128 agents first), 96 nodes/scene, dense per-scene attention.
// Single cooperative kernel, 4 phases separated by grid.sync():
//   P0: V = relu(nodes@Wv), Qb = agents@Wq, base = agents@W1   (86 blocks)
//   PA: per (scene,head,half) attention -> AO                  (96 blocks)
//   PB: y1 partial K-slices = AO@Wout1                          (48 blocks)
//   PC: per-agent tail: relu-sum, @Wout2, +base, LN, @W2, +res (128 blocks)
// ws floats: V[768][768] | Qb[128][768] | base[128][128] | AO[128][768] | y1p[12][128][128]

struct SmemP0 { float Ast[128][64]; float Bst[128][132]; };            // 100352 B
struct SmemPA { float Ns[96][132]; float Vh[96][68]; float Qs[16][132];
                float Tt[16][132]; float Sm[16][100]; float Wc[32][132]; }; // 116992 B
struct SmemPB { float As[64][68]; float Bs[64][68]; };                 // 34816 B
struct SmemPC { float y1s[128]; float nr[128]; float br[128];
                float hb[128]; float ps[512]; float red[4]; };

__global__ __launch_bounds__(512) void mega(
    const float* __restrict__ agents, const float* __restrict__ lanes,
    const float* __restrict__ Wq, const float* __restrict__ Wk,
    const float* __restrict__ Wv, const float* __restrict__ Wout1,
    const float* __restrict__ Wout2, const float* __restrict__ W1,
    const float* __restrict__ ln_g, const float* __restrict__ ln_b,
    const float* __restrict__ W2, float* __restrict__ V,
    float* __restrict__ Qb, float* __restrict__ base,
    float* __restrict__ AO, float* __restrict__ y1p,
    float* __restrict__ out)
{
    __shared__ __align__(16) char smem[119808];   // max phase need: PA 116992 B
    cg::grid_group grid = cg::this_grid();
    const int tid = threadIdx.x;
    const int bid = blockIdx.x;

    // =========== Phase 0: V / Qb / base GEMM tiles (64 rows x 128 cols) ====
    if (bid < 86) {
        SmemP0& S = *reinterpret_cast<SmemP0*>(smem);
        const float* W; float* Out;
        int r0, wc0, wstride, dstride; bool dorelu = false;
        if (bid < 72) {                       // V: 12 rb x 6 cb
            const int rb = bid % 12, cb = bid / 12;
            r0 = rb * 64; W = Wv; wc0 = cb * 128; wstride = 768;
            Out = V; dstride = 768; dorelu = true;
        } else if (bid < 84) {                // Qb: 2 rb x 6 cb
            const int idx = bid - 72;
            r0 = (idx & 1) * 64; W = Wq; wc0 = (idx >> 1) * 128; wstride = 768;
            Out = Qb; dstride = 768;
        } else {                              // base: 2 rb x full 128 cols
            const int idx = bid - 84;
            r0 = idx * 64; W = W1; wc0 = 0; wstride = 128;
            Out = base; dstride = 128;
        }

        // stage A (64 rows x 128 k) transposed: 4 f4/thread
        {
            const int row = tid >> 3, kq = tid & 7;
            const int gr = r0 + row;
            const float* src = (gr < 128) ? (agents + (size_t)gr * 128)
                                          : (lanes + (size_t)(gr - 128) * 128);
            #pragma unroll
            for (int j = 0; j < 4; ++j) {
                const int k0 = kq * 4 + j * 32;
                const float4 a = *(const float4*)(src + k0);
                S.Ast[k0 + 0][row] = a.x; S.Ast[k0 + 1][row] = a.y;
                S.Ast[k0 + 2][row] = a.z; S.Ast[k0 + 3][row] = a.w;
            }
        }
        // stage B (128 k x 128 cols): 8 f4/thread, coalesced
        {
            const int kr = tid >> 5, c4 = tid & 31;
            #pragma unroll
            for (int i = 0; i < 8; ++i) {
                const int k = kr + 16 * i;
                *(float4*)&S.Bst[k][c4 * 4] =
                    *(const float4*)(W + (size_t)k * wstride + wc0 + c4 * 4);
            }
        }
        __syncthreads();

        const int tx = tid & 31, ty = tid >> 5;   // 32 f4-cols x 16 row-groups
        float acc[4][4] = {};
        #pragma unroll 8
        for (int k = 0; k < 128; ++k) {
            const float4 a = *(const float4*)&S.Ast[k][ty * 4];
            const float4 b = *(const float4*)&S.Bst[k][tx * 4];
            const float av[4] = {a.x, a.y, a.z, a.w};
            #pragma unroll
            for (int i = 0; i < 4; ++i) {
                acc[i][0] += av[i] * b.x; acc[i][1] += av[i] * b.y;
                acc[i][2] += av[i] * b.z; acc[i][3] += av[i] * b.w;
            }
        }
        #pragma unroll
        for (int i = 0; i < 4; ++i) {
            float4 v = make_float4(acc[i][0], acc[i][1], acc[i][2], acc[i][3]);
            if (dorelu) {
                v.x = fmaxf(v.x, 0.f); v.y = fmaxf(v.y, 0.f);
                v.z = fmaxf(v.z, 0.f); v.w = fmaxf(v.w, 0.f);
            }
            *(float4*)(Out + (size_t)(r0 + ty * 4 + i) * dstride + wc0 + tx * 4) = v;
        }
    }
    grid.sync();

    // =========== Phase A: attention, (scene, head, half) ===================
    if (bid < 96) {
        SmemPA& S = *reinterpret_cast<SmemPA*>(smem);
        const int s = bid / 12, r12 = bid % 12;
        const int h = r12 >> 1, half = r12 & 1;

        #pragma unroll
        for (int ii = 0; ii < 6; ++ii) {          // Ns: 96 x 32 f4
            const int idx = tid + ii * 512;
            const int n = idx >> 5, c4 = idx & 31;
            const float* src = (n < 16) ? (agents + (size_t)(s * 16 + n) * 128)
                                        : (lanes + (size_t)(s * 80 + n - 16) * 128);
            *(float4*)&S.Ns[n][c4 * 4] = *(const float4*)(src + c4 * 4);
        }
        #pragma unroll
        for (int ii = 0; ii < 3; ++ii) {          // Vh: 96 x 16 f4
            const int idx = tid + ii * 512;
            const int n = idx >> 4, c4 = idx & 15;
            const int g = (n < 16) ? (s * 16 + n) : (128 + s * 80 + (n - 16));
            *(float4*)&S.Vh[n][c4 * 4] =
                *(const float4*)(V + (size_t)g * 768 + h * 128 + half * 64 + c4 * 4);
        }
        {
            const int r = tid >> 5, c4 = tid & 31; // Qs: 16 x 32 f4
            *(float4*)&S.Qs[r][c4 * 4] =
                *(const float4*)(Qb + (size_t)(s * 16 + r) * 768 + h * 128 + c4 * 4);
        }
        __syncthreads();

        // T[r][k] = sum_c Q[r][c] * Wk[k][h*128+c], 4 chunks of 32 k-rows
        const int r = tid >> 5, kc = tid & 31;
        for (int ck = 0; ck < 4; ++ck) {
            {
                const int i0 = tid * 2;
                #pragma unroll
                for (int ii = 0; ii < 2; ++ii) {
                    const int idx = i0 + ii;
                    const int row = idx >> 5, c4 = idx & 31;
                    *(float4*)&S.Wc[row][c4 * 4] =
                        *(const float4*)(Wk + (size_t)(ck * 32 + row) * 768 +
                                         h * 128 + c4 * 4);
                }
            }
            __syncthreads();
            {
                float acc = 0.f;
                #pragma unroll 8
                for (int c4 = 0; c4 < 32; ++c4) {
                    const float4 q = *(const float4*)&S.Qs[r][c4 * 4];
                    const float4 w = *(const float4*)&S.Wc[kc][c4 * 4];
                    acc += q.x * w.x + q.y * w.y + q.z * w.z + q.w * w.w;
                }
                S.Tt[r][ck * 32 + kc] = acc;
            }
            __syncthreads();
        }

        // S row i over j in {jc, jc+32, jc+64}; softmax in the owning half-wave
        {
            const int i = r, jc = kc;
            float s0 = 0, s1 = 0, s2 = 0;
            #pragma unroll 4
            for (int kk = 0; kk < 32; ++kk) {
                const float4 t4 = *(const float4*)&S.Tt[i][kk * 4];
                const float4 a  = *(const float4*)&S.Ns[jc][kk * 4];
                const float4 bb = *(const float4*)&S.Ns[jc + 32][kk * 4];
                const float4 c  = *(const float4*)&S.Ns[jc + 64][kk * 4];
                s0 += t4.x*a.x  + t4.y*a.y  + t4.z*a.z  + t4.w*a.w;
                s1 += t4.x*bb.x + t4.y*bb.y + t4.z*bb.z + t4.w*bb.w;
                s2 += t4.x*c.x  + t4.y*c.y  + t4.z*c.z  + t4.w*c.w;
            }
            const float scale = 0.088388347648318447f;   // 128^-0.5
            s0 *= scale; s1 *= scale; s2 *= scale;
            float m = fmaxf(fmaxf(s0, s1), s2);
            #pragma unroll
            for (int o = 16; o >= 1; o >>= 1) m = fmaxf(m, __shfl_xor(m, o, 32));
            const float e0 = __expf(s0 - m), e1 = __expf(s1 - m), e2 = __expf(s2 - m);
            float sum = e0 + e1 + e2;
            #pragma unroll
            for (int o = 16; o >= 1; o >>= 1) sum += __shfl_xor(sum, o, 32);
            const float inv = 1.0f / sum;
            S.Sm[i][jc]      = e0 * inv;
            S.Sm[i][jc + 32] = e1 * inv;
            S.Sm[i][jc + 64] = e2 * inv;
        }

        // O_half = P @ V_half (row i owned by same half-wave)
        {
            const int i = r, d = kc;
            float o0 = 0, o1 = 0;
            #pragma unroll 4
            for (int j = 0; j < 96; ++j) {
                const float p = S.Sm[i][j];
                const float2 v = *(const float2*)&S.Vh[j][2 * d];
                o0 += p * v.x; o1 += p * v.y;
            }
            float* dst = AO + (size_t)(s * 16 + i) * 768 + h * 128 + half * 64 + 2 * d;
            *(float2*)dst = make_float2(o0, o1);
        }
    }
    grid.sync();

    // =========== Phase B: y1 partial slices, 48 blocks ====================
    if (bid < 48) {
        SmemPB& S = *reinterpret_cast<SmemPB*>(smem);
        const int ks = bid >> 2, quad = bid & 3;
        const int m0 = (quad >> 1) * 64, n0 = (quad & 1) * 64;

        {   // A transposed: As[k][m] = AO[m0+row][ks*64+k], 2 f4/thread
            const int row = tid >> 3, kq = tid & 7;
            #pragma unroll
            for (int j = 0; j < 2; ++j) {
                const int k0 = kq * 4 + j * 32;
                const float4 a =
                    *(const float4*)(AO + (size_t)(m0 + row) * 768 + ks * 64 + k0);
                S.As[k0 + 0][row] = a.x; S.As[k0 + 1][row] = a.y;
                S.As[k0 + 2][row] = a.z; S.As[k0 + 3][row] = a.w;
            }
        }
        {   // B: Bs[k][n] = Wout1[ks*64+k][n0+n], 2 f4/thread
            const int kr = tid >> 4, c4 = tid & 15;
            #pragma unroll
            for (int i = 0; i < 2; ++i) {
                const int k = kr + 32 * i;
                *(float4*)&S.Bs[k][c4 * 4] =
                    *(const float4*)(Wout1 + (size_t)(ks * 64 + k) * 128 + n0 + c4 * 4);
            }
        }
        __syncthreads();

        const int tx = tid & 15, ty = tid >> 4;   // 16 f4-cols x 32 row-pairs
        float acc[2][4] = {};
        #pragma unroll 8
        for (int k = 0; k < 64; ++k) {
            const float2 a = *(const float2*)&S.As[k][ty * 2];
            const float4 b = *(const float4*)&S.Bs[k][tx * 4];
            acc[0][0] += a.x * b.x; acc[0][1] += a.x * b.y;
            acc[0][2] += a.x * b.z; acc[0][3] += a.x * b.w;
            acc[1][0] += a.y * b.x; acc[1][1] += a.y * b.y;
            acc[1][2] += a.y * b.z; acc[1][3] += a.y * b.w;
        }
        float* dst = y1p + (size_t)ks * 16384 + (size_t)m0 * 128 + n0;
        #pragma unroll
        for (int rr = 0; rr < 2; ++rr)
            *(float4*)(dst + (size_t)(ty * 2 + rr) * 128 + tx * 4) =
                make_float4(acc[rr][0], acc[rr][1], acc[rr][2], acc[rr][3]);
    }
    grid.sync();

    // =========== Phase C: per-agent tail, 128 blocks ======================
    {
        SmemPC& S = *reinterpret_cast<SmemPC*>(smem);
        const int a = bid;

        if (tid < 32) {
            float4 acc = make_float4(0, 0, 0, 0);
            #pragma unroll
            for (int ks = 0; ks < 12; ++ks) {
                const float4 v = *(const float4*)(y1p + (size_t)ks * 16384 +
                                                  (size_t)a * 128 + tid * 4);
                acc.x += v.x; acc.y += v.y; acc.z += v.z; acc.w += v.w;
            }
            S.y1s[tid * 4 + 0] = fmaxf(acc.x, 0.f);
            S.y1s[tid * 4 + 1] = fmaxf(acc.y, 0.f);
            S.y1s[tid * 4 + 2] = fmaxf(acc.z, 0.f);
            S.y1s[tid * 4 + 3] = fmaxf(acc.w, 0.f);
        } else if (tid < 64) {
            const int t = tid - 32;
            *(float4*)&S.nr[t * 4] = *(const float4*)(agents + (size_t)a * 128 + t * 4);
        } else if (tid < 96) {
            const int t = tid - 64;
            *(float4*)&S.br[t * 4] = *(const float4*)(base + (size_t)a * 128 + t * 4);
        }
        __syncthreads();

        const int d = tid & 127, g = tid >> 7;    // 4-way split-k
        {
            const int k0 = g * 32;
            float p = 0.f;
            #pragma unroll 8
            for (int k = 0; k < 32; ++k)
                p += S.y1s[k0 + k] * Wout2[(size_t)(k0 + k) * 128 + d];
            S.ps[tid] = p;
        }
        __syncthreads();

        float tval = 0.f;
        if (tid < 128)
            tval = S.ps[d] + S.ps[128 + d] + S.ps[256 + d] + S.ps[384 + d] + S.br[d];
        float s1 = tval, s2 = tval * tval;
        #pragma unroll
        for (int o = 32; o >= 1; o >>= 1) {
            s1 += __shfl_xor(s1, o); s2 += __shfl_xor(s2, o);
        }
        if (tid < 128 && (tid & 63) == 0) {
            S.red[(tid >> 6) * 2] = s1; S.red[(tid >> 6) * 2 + 1] = s2;
        }
        __syncthreads();
        if (tid < 128) {
            const float S1 = S.red[0] + S.red[2], S2 = S.red[1] + S.red[3];
            const float mu  = S1 * (1.0f / 128.0f);
            const float var = S2 * (1.0f / 128.0f) - mu * mu;
            const float rin = rsqrtf(var + LN_EPS);
            S.hb[tid] = fmaxf((tval - mu) * rin * ln_g[tid] + ln_b[tid], 0.0f);
        }
        __syncthreads();

        {
            const int k0 = g * 32;
            float p = 0.f;
            #pragma unroll 8
            for (int k = 0; k < 32; ++k)
                p += S.hb[k0 + k] * W2[(size_t)(k0 + k) * 128 + d];
            S.ps[tid] = p;
        }
        __syncthreads();
        if (tid < 128)
            out[(size_t)a * 128 + d] =
                fmaxf(S.ps[d] + S.ps[128 + d] + S.ps[256 + d] + S.ps[384 + d] +
                      S.nr[d], 0.0f);
    }
}

// ---------------------------------------------------------------------------
extern "C" void kernel_launch(void* const* d_in, const int* in_sizes, int n_in,
                              void* d_out, int out_size, void* d_ws, size_t ws_size,
                              hipStream_t stream)
{
    const float* agents = (const float*)d_in[0];
    const float* lanes  = (const float*)d_in[1];
    const float* Wq     = (const float*)d_in[2];
    const float* Wk     = (const float*)d_in[3];
    const float* Wv     = (const float*)d_in[4];
    const float* Wout1  = (const float*)d_in[5];
    const float* Wout2  = (const float*)d_in[6];
    const float* W1     = (const float*)d_in[7];
    const float* ln_g   = (const float*)d_in[8];
    const float* ln_b   = (const float*)d_in[9];
    const float* W2     = (const float*)d_in[10];
    // d_in[11], d_in[12] = hi, wi — static dense per-scene structure, unused.

    float* ws = (float*)d_ws;
    float* V    = ws;                   // [768][768]
    float* Qb   = V + 768 * 768;        // [128][768]
    float* base = Qb + 128 * 768;       // [128][128]
    float* AO   = base + 128 * 128;     // [128][768]
    float* y1p  = AO + 128 * 768;       // [12][128][128]
    float* outp = (float*)d_out;

    void* args[] = {
        (void*)&agents, (void*)&lanes, (void*)&Wq, (void*)&Wk, (void*)&Wv,
        (void*)&Wout1, (void*)&Wout2, (void*)&W1, (void*)&ln_g, (void*)&ln_b,
        (void*)&W2, (void*)&V, (void*)&Qb, (void*)&base, (void*)&AO,
        (void*)&y1p, (void*)&outp
    };
    hipLaunchCooperativeKernel((void*)mega, dim3(128), dim3(512), args, 0, stream);
}

// Round 7
// 112.734 us; speedup vs baseline: 1.5988x; 1.5988x over previous
//
#include <hip/hip_runtime.h>
#include <math.h>

#define LN_EPS 1e-5f

// Problem: B=8 scenes, A=16 agents, L=80 lanes, D=128, H=6.
// N=768 nodes (128 agents first), 96 nodes/scene, dense per-scene attention.
// Two dispatches:
//  1) k_attn_all: per (scene,head,half) block computes Q, V-half, T=Q@Wk^T,
//     S, softmax, PV entirely from LDS-staged operands -> AO.
//  2) k_tail: per-agent epilogue (y1, y2, base, LN, W2, residual).
// ws floats: AO[128][768] only.

// ---------------------------------------------------------------------------
__global__ __launch_bounds__(512) void k_attn_all(
    const float* __restrict__ agents, const float* __restrict__ lanes,
    const float* __restrict__ Wq, const float* __restrict__ Wk,
    const float* __restrict__ Wv, float* __restrict__ AO)
{
    __shared__ float Ns[96][132];   // raw nodes            50.7 KB
    __shared__ float Vh[96][68];    // V half (64 cols)     26.1 KB
    __shared__ float Qs[16][132];   // Q rows                8.5 KB
    __shared__ float Tt[16][132];   // T = Q @ Wk_h^T        8.5 KB
    __shared__ float Sm[16][100];   // P                     6.4 KB
    __shared__ float Wc[64][132];   // weight chunk (reused) 33.8 KB   => 134 KB

    const int tid = threadIdx.x;
    const int b = blockIdx.x;
    const int s = b / 12, r12 = b % 12;
    const int h = r12 >> 1, half = r12 & 1;

    // ---- stage raw nodes of scene s (96 x 32 f4)
    #pragma unroll
    for (int ii = 0; ii < 6; ++ii) {
        const int idx = tid + ii * 512;
        const int n = idx >> 5, c4 = idx & 31;
        const float* src = (n < 16) ? (agents + (size_t)(s * 16 + n) * 128)
                                    : (lanes + (size_t)(s * 80 + n - 16) * 128);
        *(float4*)&Ns[n][c4 * 4] = *(const float4*)(src + c4 * 4);
    }

    const int r = tid >> 5, jc = tid & 31;   // row / col-group ownership

    // ---- Q = agents_s @ Wq_h, 2 chunks of 64 k-rows through Wc
    float q0 = 0, q1 = 0, q2 = 0, q3 = 0;
    for (int ck = 0; ck < 2; ++ck) {
        __syncthreads();                       // prior Wc readers done (and Ns visible)
        #pragma unroll
        for (int ii = 0; ii < 4; ++ii) {       // 64 rows x 32 f4
            const int idx = tid + ii * 512;
            const int row = idx >> 5, c4 = idx & 31;
            *(float4*)&Wc[row][c4 * 4] =
                *(const float4*)(Wq + (size_t)(ck * 64 + row) * 768 + h * 128 + c4 * 4);
        }
        __syncthreads();
        #pragma unroll 4
        for (int kk = 0; kk < 64; ++kk) {
            const float a = Ns[r][ck * 64 + kk];
            q0 += a * Wc[kk][jc];
            q1 += a * Wc[kk][jc + 32];
            q2 += a * Wc[kk][jc + 64];
            q3 += a * Wc[kk][jc + 96];
        }
    }
    Qs[r][jc] = q0; Qs[r][jc + 32] = q1; Qs[r][jc + 64] = q2; Qs[r][jc + 96] = q3;

    // ---- V_half = relu(nodes @ Wv_h[:, half*64 .. +64)), 2 chunks
    const int rg = tid >> 4, cv = tid & 15;
    float4 va0 = make_float4(0,0,0,0), va1 = va0, va2 = va0;
    for (int ck = 0; ck < 2; ++ck) {
        __syncthreads();                       // prior Wc readers done; Qs visible later
        #pragma unroll
        for (int ii = 0; ii < 2; ++ii) {       // 64 rows x 16 f4
            const int idx = tid + ii * 512;
            const int row = idx >> 4, cc = idx & 15;
            *(float4*)&Wc[row][cc * 4] =
                *(const float4*)(Wv + (size_t)(ck * 64 + row) * 768 +
                                 h * 128 + half * 64 + cc * 4);
        }
        __syncthreads();
        #pragma unroll 4
        for (int kk = 0; kk < 64; ++kk) {
            const float4 w = *(const float4*)&Wc[kk][cv * 4];
            const float n0 = Ns[rg][ck * 64 + kk];
            const float n1 = Ns[rg + 32][ck * 64 + kk];
            const float n2 = Ns[rg + 64][ck * 64 + kk];
            va0.x += n0 * w.x; va0.y += n0 * w.y; va0.z += n0 * w.z; va0.w += n0 * w.w;
            va1.x += n1 * w.x; va1.y += n1 * w.y; va1.z += n1 * w.z; va1.w += n1 * w.w;
            va2.x += n2 * w.x; va2.y += n2 * w.y; va2.z += n2 * w.z; va2.w += n2 * w.w;
        }
    }
    va0.x = fmaxf(va0.x, 0.f); va0.y = fmaxf(va0.y, 0.f);
    va0.z = fmaxf(va0.z, 0.f); va0.w = fmaxf(va0.w, 0.f);
    va1.x = fmaxf(va1.x, 0.f); va1.y = fmaxf(va1.y, 0.f);
    va1.z = fmaxf(va1.z, 0.f); va1.w = fmaxf(va1.w, 0.f);
    va2.x = fmaxf(va2.x, 0.f); va2.y = fmaxf(va2.y, 0.f);
    va2.z = fmaxf(va2.z, 0.f); va2.w = fmaxf(va2.w, 0.f);
    *(float4*)&Vh[rg][cv * 4]      = va0;
    *(float4*)&Vh[rg + 32][cv * 4] = va1;
    *(float4*)&Vh[rg + 64][cv * 4] = va2;

    // ---- T[r][k] = Qs[r] . Wk[k][h*128:+128], 2 chunks of 64 k-rows
    for (int ck = 0; ck < 2; ++ck) {
        __syncthreads();                       // prior Wc readers done; Qs/Vh visible
        #pragma unroll
        for (int ii = 0; ii < 4; ++ii) {       // 64 rows x 32 f4
            const int idx = tid + ii * 512;
            const int row = idx >> 5, c4 = idx & 31;
            *(float4*)&Wc[row][c4 * 4] =
                *(const float4*)(Wk + (size_t)(ck * 64 + row) * 768 + h * 128 + c4 * 4);
        }
        __syncthreads();
        float a1 = 0, a2 = 0;
        #pragma unroll 4
        for (int c4i = 0; c4i < 32; ++c4i) {
            const float4 q  = *(const float4*)&Qs[r][c4i * 4];
            const float4 w1 = *(const float4*)&Wc[jc][c4i * 4];
            const float4 w2 = *(const float4*)&Wc[jc + 32][c4i * 4];
            a1 += q.x * w1.x + q.y * w1.y + q.z * w1.z + q.w * w1.w;
            a2 += q.x * w2.x + q.y * w2.y + q.z * w2.z + q.w * w2.w;
        }
        Tt[r][ck * 64 + jc]      = a1;
        Tt[r][ck * 64 + 32 + jc] = a2;
    }
    __syncthreads();

    // ---- S row i over j in {jc, jc+32, jc+64}; softmax in the owning half-wave
    {
        const int i = r;
        float s0 = 0, s1 = 0, s2 = 0;
        #pragma unroll 4
        for (int kk = 0; kk < 32; ++kk) {
            const float4 t4 = *(const float4*)&Tt[i][kk * 4];
            const float4 a  = *(const float4*)&Ns[jc][kk * 4];
            const float4 bb = *(const float4*)&Ns[jc + 32][kk * 4];
            const float4 c  = *(const float4*)&Ns[jc + 64][kk * 4];
            s0 += t4.x*a.x  + t4.y*a.y  + t4.z*a.z  + t4.w*a.w;
            s1 += t4.x*bb.x + t4.y*bb.y + t4.z*bb.z + t4.w*bb.w;
            s2 += t4.x*c.x  + t4.y*c.y  + t4.z*c.z  + t4.w*c.w;
        }
        const float scale = 0.088388347648318447f;   // 128^-0.5
        s0 *= scale; s1 *= scale; s2 *= scale;
        float m = fmaxf(fmaxf(s0, s1), s2);
        #pragma unroll
        for (int o = 16; o >= 1; o >>= 1) m = fmaxf(m, __shfl_xor(m, o, 32));
        const float e0 = __expf(s0 - m), e1 = __expf(s1 - m), e2 = __expf(s2 - m);
        float sum = e0 + e1 + e2;
        #pragma unroll
        for (int o = 16; o >= 1; o >>= 1) sum += __shfl_xor(sum, o, 32);
        const float inv = 1.0f / sum;
        Sm[i][jc]      = e0 * inv;
        Sm[i][jc + 32] = e1 * inv;
        Sm[i][jc + 64] = e2 * inv;
    }

    // ---- O_half = P @ V_half (row i owned by the same half-wave)
    {
        const int i = r, d = jc;
        float o0 = 0, o1 = 0;
        #pragma unroll 4
        for (int j = 0; j < 96; ++j) {
            const float p = Sm[i][j];
            const float2 v = *(const float2*)&Vh[j][2 * d];
            o0 += p * v.x; o1 += p * v.y;
        }
        float* dst = AO + (size_t)(s * 16 + i) * 768 + h * 128 + half * 64 + 2 * d;
        *(float2*)dst = make_float2(o0, o1);
    }
}

// ---------------------------------------------------------------------------
// Per-agent epilogue. 128 blocks x 512 threads.
__global__ __launch_bounds__(512) void k_tail(
    const float* __restrict__ AO, const float* __restrict__ agents,
    const float* __restrict__ Wout1, const float* __restrict__ Wout2,
    const float* __restrict__ W1, const float* __restrict__ ln_g,
    const float* __restrict__ ln_b, const float* __restrict__ W2,
    float* __restrict__ out)
{
    const int a = blockIdx.x;
    const int tid = threadIdx.x;
    __shared__ float AOs[768];
    __shared__ float nr[128];
    __shared__ float y1s[128];
    __shared__ float hb[128];
    __shared__ float ps[512];
    __shared__ float red[4];

    if (tid < 192) {
        *(float4*)&AOs[tid * 4] = *(const float4*)(AO + (size_t)a * 768 + tid * 4);
    } else if (tid < 224) {
        const int t = tid - 192;
        *(float4*)&nr[t * 4] = *(const float4*)(agents + (size_t)a * 128 + t * 4);
    }
    __syncthreads();

    const int d = tid & 127, g = tid >> 7;

    // ---- y1 = relu(AO @ Wout1), 4-way split over K=768 (192 each)
    {
        const int k0 = g * 192;
        float p = 0.f;
        #pragma unroll 8
        for (int k = 0; k < 192; ++k)
            p += AOs[k0 + k] * Wout1[(size_t)(k0 + k) * 128 + d];
        ps[tid] = p;
    }
    __syncthreads();
    if (tid < 128) y1s[d] = fmaxf(ps[d] + ps[128 + d] + ps[256 + d] + ps[384 + d], 0.f);
    __syncthreads();

    // ---- g<2: y2 halves (y1s@Wout2); g>=2: base halves (nr@W1)
    {
        const float* src = (g < 2) ? y1s : nr;
        const float* Wm  = (g < 2) ? Wout2 : W1;
        const int k0 = (g & 1) * 64;
        float p = 0.f;
        #pragma unroll 8
        for (int k = 0; k < 64; ++k)
            p += src[k0 + k] * Wm[(size_t)(k0 + k) * 128 + d];
        ps[tid] = p;
    }
    __syncthreads();

    // ---- t = y2 + base ; LayerNorm over 128 (threads 0..127 span waves 0,1)
    float tval = 0.f;
    if (tid < 128) tval = ps[d] + ps[128 + d] + ps[256 + d] + ps[384 + d];
    float s1 = tval, s2 = tval * tval;
    #pragma unroll
    for (int o = 32; o >= 1; o >>= 1) { s1 += __shfl_xor(s1, o); s2 += __shfl_xor(s2, o); }
    if (tid < 128 && (tid & 63) == 0) {
        red[(tid >> 6) * 2] = s1; red[(tid >> 6) * 2 + 1] = s2;
    }
    __syncthreads();
    if (tid < 128) {
        const float S1 = red[0] + red[2], S2 = red[1] + red[3];
        const float mu  = S1 * (1.0f / 128.0f);
        const float var = S2 * (1.0f / 128.0f) - mu * mu;
        const float rin = rsqrtf(var + LN_EPS);
        hb[d] = fmaxf((tval - mu) * rin * ln_g[d] + ln_b[d], 0.0f);
    }
    __syncthreads();

    // ---- out = relu(hb @ W2 + agents), 4-way split over K=128
    {
        const int k0 = g * 32;
        float p = 0.f;
        #pragma unroll 8
        for (int k = 0; k < 32; ++k)
            p += hb[k0 + k] * W2[(size_t)(k0 + k) * 128 + d];
        ps[tid] = p;
    }
    __syncthreads();
    if (tid < 128)
        out[(size_t)a * 128 + d] =
            fmaxf(ps[d] + ps[128 + d] + ps[256 + d] + ps[384 + d] + nr[d], 0.0f);
}

// ---------------------------------------------------------------------------
extern "C" void kernel_launch(void* const* d_in, const int* in_sizes, int n_in,
                              void* d_out, int out_size, void* d_ws, size_t ws_size,
                              hipStream_t stream)
{
    const float* agents = (const float*)d_in[0];
    const float* lanes  = (const float*)d_in[1];
    const float* Wq     = (const float*)d_in[2];
    const float* Wk     = (const float*)d_in[3];
    const float* Wv     = (const float*)d_in[4];
    const float* Wout1  = (const float*)d_in[5];
    const float* Wout2  = (const float*)d_in[6];
    const float* W1     = (const float*)d_in[7];
    const float* ln_g   = (const float*)d_in[8];
    const float* ln_b   = (const float*)d_in[9];
    const float* W2     = (const float*)d_in[10];
    // d_in[11], d_in[12] = hi, wi — static dense per-scene structure, unused.

    float* AO   = (float*)d_ws;         // [128][768]
    float* outp = (float*)d_out;

    k_attn_all<<<96, 512, 0, stream>>>(agents, lanes, Wq, Wk, Wv, AO);
    k_tail    <<<128, 512, 0, stream>>>(AO, agents, Wout1, Wout2, W1,
                                        ln_g, ln_b, W2, outp);
}

// Round 8
// 109.902 us; speedup vs baseline: 1.6400x; 1.0258x over previous
//
#include <hip/hip_runtime.h>
#include <math.h>

#define LN_EPS 1e-5f

// Problem: B=8 scenes, A=16 agents, L=80 lanes, D=128, H=6.
// N=768 nodes (128 agents first), 96 nodes/scene, dense per-scene attention.
// Three dispatches:
//  1) k_qkv : V = relu(nodes@Wv), Kb = nodes@Wk, Qb = agents@Wq  (312 blocks)
//  2) k_attn3: per (scene,head,half): S = Q@K^T, softmax, P@V -> AO
//  3) k_tail : per-agent epilogue (y1, y2, base, LN, W2, residual)
// ws floats: V[768][768] | Kb[768][768] | Qb[128][768] | AO[128][768]

// ---------------------------------------------------------------------------
// Kernel 1: 64x64 tiles, full LDS staging, 4x4 register tile (R5-proven body).
//   blocks 0..143  : V  = relu(nodes @ Wv)   (12 rb x 12 cb)
//   blocks 144..287: Kb = nodes @ Wk         (12 rb x 12 cb)
//   blocks 288..311: Qb = agents @ Wq        (2 rb x 12 cb)
__global__ __launch_bounds__(256) void k_qkv(
    const float* __restrict__ agents, const float* __restrict__ lanes,
    const float* __restrict__ Wv, const float* __restrict__ Wk,
    const float* __restrict__ Wq, float* __restrict__ V,
    float* __restrict__ Kb, float* __restrict__ Qb)
{
    __shared__ float As[128][68];   // [k][row] 34.8 KB
    __shared__ float Bs[128][68];   // [k][col] 34.8 KB

    const int tid = threadIdx.x;
    const int bid = blockIdx.x;

    const float* W;
    float* Out;
    int r0, wc0;
    bool dorelu = false;
    if (bid < 144) {
        const int rb = bid % 12, cb = bid / 12;
        r0 = rb * 64; W = Wv; wc0 = cb * 64; Out = V; dorelu = true;
    } else if (bid < 288) {
        const int idx = bid - 144;
        const int rb = idx % 12, cb = idx / 12;
        r0 = rb * 64; W = Wk; wc0 = cb * 64; Out = Kb;
    } else {
        const int idx = bid - 288;
        r0 = (idx & 1) * 64; W = Wq; wc0 = (idx >> 1) * 64; Out = Qb;
    }

    // stage A (64 rows x 128 k) transposed
    {
        const int row = tid >> 2, kv = tid & 3;
        const int gr = r0 + row;
        const float* src = (gr < 128) ? (agents + (size_t)gr * 128)
                                      : (lanes + (size_t)(gr - 128) * 128);
        #pragma unroll
        for (int j = 0; j < 8; ++j) {
            const int k0 = kv * 4 + j * 16;
            const float4 a = *(const float4*)(src + k0);
            As[k0 + 0][row] = a.x; As[k0 + 1][row] = a.y;
            As[k0 + 2][row] = a.z; As[k0 + 3][row] = a.w;
        }
    }
    // stage B (128 k x 64 cols) direct, coalesced
    {
        const int kr = tid >> 4, c4 = tid & 15;
        #pragma unroll
        for (int i = 0; i < 8; ++i) {
            const int k = kr + 16 * i;
            *(float4*)&Bs[k][c4 * 4] =
                *(const float4*)(W + (size_t)k * 768 + wc0 + c4 * 4);
        }
    }
    __syncthreads();

    const int tx = tid & 15, ty = tid >> 4;
    float acc[4][4] = {};
    #pragma unroll 8
    for (int k = 0; k < 128; ++k) {
        const float4 a = *(const float4*)&As[k][ty * 4];
        const float4 b = *(const float4*)&Bs[k][tx * 4];
        const float av[4] = {a.x, a.y, a.z, a.w};
        #pragma unroll
        for (int i = 0; i < 4; ++i) {
            acc[i][0] += av[i] * b.x; acc[i][1] += av[i] * b.y;
            acc[i][2] += av[i] * b.z; acc[i][3] += av[i] * b.w;
        }
    }
    #pragma unroll
    for (int i = 0; i < 4; ++i) {
        float4 v = make_float4(acc[i][0], acc[i][1], acc[i][2], acc[i][3]);
        if (dorelu) {
            v.x = fmaxf(v.x, 0.f); v.y = fmaxf(v.y, 0.f);
            v.z = fmaxf(v.z, 0.f); v.w = fmaxf(v.w, 0.f);
        }
        *(float4*)(Out + (size_t)(r0 + ty * 4 + i) * 768 + wc0 + tx * 4) = v;
    }
}

// ---------------------------------------------------------------------------
// Kernel 2: attention from precomputed Q/K/V. 96 blocks = (scene,head,half).
// One staging barrier; S/softmax/PV all owned by half-wave of row i.
__global__ __launch_bounds__(512) void k_attn3(
    const float* __restrict__ Kb, const float* __restrict__ V,
    const float* __restrict__ Qb, float* __restrict__ AO)
{
    __shared__ float Ks[96][136];   // K rows, stride 136 -> 2-way (free) banks  52.2 KB
    __shared__ float Vh[96][68];    // V half (64 cols)                          26.1 KB
    __shared__ float Qs[16][132];   // Q rows                                     8.4 KB
    __shared__ float Sm[16][100];   // P                                          6.4 KB

    const int tid = threadIdx.x;
    const int b = blockIdx.x;
    const int s = b / 12, r12 = b % 12;
    const int h = r12 >> 1, half = r12 & 1;

    // ---- stage Q (16x32 f4), K (96x32 f4), V-half (96x16 f4)
    {
        const int r = tid >> 5, c4 = tid & 31;
        *(float4*)&Qs[r][c4 * 4] =
            *(const float4*)(Qb + (size_t)(s * 16 + r) * 768 + h * 128 + c4 * 4);
    }
    #pragma unroll
    for (int ii = 0; ii < 6; ++ii) {
        const int idx = tid + ii * 512;
        const int n = idx >> 5, c4 = idx & 31;
        const int g = (n < 16) ? (s * 16 + n) : (128 + s * 80 + (n - 16));
        *(float4*)&Ks[n][c4 * 4] =
            *(const float4*)(Kb + (size_t)g * 768 + h * 128 + c4 * 4);
    }
    #pragma unroll
    for (int ii = 0; ii < 3; ++ii) {
        const int idx = tid + ii * 512;
        const int n = idx >> 4, c4 = idx & 15;
        const int g = (n < 16) ? (s * 16 + n) : (128 + s * 80 + (n - 16));
        *(float4*)&Vh[n][c4 * 4] =
            *(const float4*)(V + (size_t)g * 768 + h * 128 + half * 64 + c4 * 4);
    }
    __syncthreads();

    const int i = tid >> 5, jc = tid & 31;   // row / col ownership (half-wave)

    // ---- S[i][j] for j in {jc, jc+32, jc+64}; Q broadcast, K 2-way banks
    {
        float s0 = 0, s1 = 0, s2 = 0;
        #pragma unroll 4
        for (int kk = 0; kk < 32; ++kk) {
            const float4 q  = *(const float4*)&Qs[i][kk * 4];
            const float4 k0 = *(const float4*)&Ks[jc][kk * 4];
            const float4 k1 = *(const float4*)&Ks[jc + 32][kk * 4];
            const float4 k2 = *(const float4*)&Ks[jc + 64][kk * 4];
            s0 += q.x*k0.x + q.y*k0.y + q.z*k0.z + q.w*k0.w;
            s1 += q.x*k1.x + q.y*k1.y + q.z*k1.z + q.w*k1.w;
            s2 += q.x*k2.x + q.y*k2.y + q.z*k2.z + q.w*k2.w;
        }
        const float scale = 0.088388347648318447f;   // 128^-0.5
        s0 *= scale; s1 *= scale; s2 *= scale;
        float m = fmaxf(fmaxf(s0, s1), s2);
        #pragma unroll
        for (int o = 16; o >= 1; o >>= 1) m = fmaxf(m, __shfl_xor(m, o, 32));
        const float e0 = __expf(s0 - m), e1 = __expf(s1 - m), e2 = __expf(s2 - m);
        float sum = e0 + e1 + e2;
        #pragma unroll
        for (int o = 16; o >= 1; o >>= 1) sum += __shfl_xor(sum, o, 32);
        const float inv = 1.0f / sum;
        Sm[i][jc]      = e0 * inv;
        Sm[i][jc + 32] = e1 * inv;
        Sm[i][jc + 64] = e2 * inv;
    }
    // no barrier: PV for row i runs on the same 32 lanes that wrote Sm[i][*]

    // ---- O_half = P @ V_half : row i, 2 cols per thread
    {
        const int d = jc;
        float o0 = 0, o1 = 0;
        #pragma unroll 4
        for (int j = 0; j < 96; ++j) {
            const float p = Sm[i][j];
            const float2 v = *(const float2*)&Vh[j][2 * d];
            o0 += p * v.x; o1 += p * v.y;
        }
        float* dst = AO + (size_t)(s * 16 + i) * 768 + h * 128 + half * 64 + 2 * d;
        *(float2*)dst = make_float2(o0, o1);
    }
}

// ---------------------------------------------------------------------------
// Kernel 3: per-agent epilogue. 128 blocks x 512 threads (R7-verified body).
__global__ __launch_bounds__(512) void k_tail(
    const float* __restrict__ AO, const float* __restrict__ agents,
    const float* __restrict__ Wout1, const float* __restrict__ Wout2,
    const float* __restrict__ W1, const float* __restrict__ ln_g,
    const float* __restrict__ ln_b, const float* __restrict__ W2,
    float* __restrict__ out)
{
    const int a = blockIdx.x;
    const int tid = threadIdx.x;
    __shared__ float AOs[768];
    __shared__ float nr[128];
    __shared__ float y1s[128];
    __shared__ float hb[128];
    __shared__ float ps[512];
    __shared__ float red[4];

    if (tid < 192) {
        *(float4*)&AOs[tid * 4] = *(const float4*)(AO + (size_t)a * 768 + tid * 4);
    } else if (tid < 224) {
        const int t = tid - 192;
        *(float4*)&nr[t * 4] = *(const float4*)(agents + (size_t)a * 128 + t * 4);
    }
    __syncthreads();

    const int d = tid & 127, g = tid >> 7;

    // ---- y1 = relu(AO @ Wout1), 4-way split over K=768 (192 each)
    {
        const int k0 = g * 192;
        float p = 0.f;
        #pragma unroll 8
        for (int k = 0; k < 192; ++k)
            p += AOs[k0 + k] * Wout1[(size_t)(k0 + k) * 128 + d];
        ps[tid] = p;
    }
    __syncthreads();
    if (tid < 128) y1s[d] = fmaxf(ps[d] + ps[128 + d] + ps[256 + d] + ps[384 + d], 0.f);
    __syncthreads();

    // ---- g<2: y2 halves (y1s@Wout2); g>=2: base halves (nr@W1)
    {
        const float* src = (g < 2) ? y1s : nr;
        const float* Wm  = (g < 2) ? Wout2 : W1;
        const int k0 = (g & 1) * 64;
        float p = 0.f;
        #pragma unroll 8
        for (int k = 0; k < 64; ++k)
            p += src[k0 + k] * Wm[(size_t)(k0 + k) * 128 + d];
        ps[tid] = p;
    }
    __syncthreads();

    // ---- t = y2 + base ; LayerNorm over 128 (threads 0..127 span waves 0,1)
    float tval = 0.f;
    if (tid < 128) tval = ps[d] + ps[128 + d] + ps[256 + d] + ps[384 + d];
    float s1 = tval, s2 = tval * tval;
    #pragma unroll
    for (int o = 32; o >= 1; o >>= 1) { s1 += __shfl_xor(s1, o); s2 += __shfl_xor(s2, o); }
    if (tid < 128 && (tid & 63) == 0) {
        red[(tid >> 6) * 2] = s1; red[(tid >> 6) * 2 + 1] = s2;
    }
    __syncthreads();
    if (tid < 128) {
        const float S1 = red[0] + red[2], S2 = red[1] + red[3];
        const float mu  = S1 * (1.0f / 128.0f);
        const float var = S2 * (1.0f / 128.0f) - mu * mu;
        const float rin = rsqrtf(var + LN_EPS);
        hb[d] = fmaxf((tval - mu) * rin * ln_g[d] + ln_b[d], 0.0f);
    }
    __syncthreads();

    // ---- out = relu(hb @ W2 + agents), 4-way split over K=128
    {
        const int k0 = g * 32;
        float p = 0.f;
        #pragma unroll 8
        for (int k = 0; k < 32; ++k)
            p += hb[k0 + k] * W2[(size_t)(k0 + k) * 128 + d];
        ps[tid] = p;
    }
    __syncthreads();
    if (tid < 128)
        out[(size_t)a * 128 + d] =
            fmaxf(ps[d] + ps[128 + d] + ps[256 + d] + ps[384 + d] + nr[d], 0.0f);
}

// ---------------------------------------------------------------------------
extern "C" void kernel_launch(void* const* d_in, const int* in_sizes, int n_in,
                              void* d_out, int out_size, void* d_ws, size_t ws_size,
                              hipStream_t stream)
{
    const float* agents = (const float*)d_in[0];
    const float* lanes  = (const float*)d_in[1];
    const float* Wq     = (const float*)d_in[2];
    const float* Wk     = (const float*)d_in[3];
    const float* Wv     = (const float*)d_in[4];
    const float* Wout1  = (const float*)d_in[5];
    const float* Wout2  = (const float*)d_in[6];
    const float* W1     = (const float*)d_in[7];
    const float* ln_g   = (const float*)d_in[8];
    const float* ln_b   = (const float*)d_in[9];
    const float* W2     = (const float*)d_in[10];
    // d_in[11], d_in[12] = hi, wi — static dense per-scene structure, unused.

    float* ws = (float*)d_ws;
    float* V    = ws;                   // [768][768]
    float* Kb   = V + 768 * 768;        // [768][768]
    float* Qb   = Kb + 768 * 768;       // [128][768]
    float* AO   = Qb + 128 * 768;       // [128][768]
    float* outp = (float*)d_out;

    k_qkv  <<<312, 256, 0, stream>>>(agents, lanes, Wv, Wk, Wq, V, Kb, Qb);
    k_attn3<<<96, 512, 0, stream>>>(Kb, V, Qb, AO);
    k_tail <<<128, 512, 0, stream>>>(AO, agents, Wout1, Wout2, W1,
                                     ln_g, ln_b, W2, outp);
}